// Round 3
// baseline (810.176 us; speedup 1.0000x reference)
//
#include <hip/hip_runtime.h>
#include <hip/hip_bf16.h>

typedef __bf16 bf16_t;
typedef bf16_t bf16x8 __attribute__((ext_vector_type(8)));
typedef float  f32x4  __attribute__((ext_vector_type(4)));

#define S_LEN  2048
#define DMODEL 2048
#define NH     16
#define DH     128
#define BATCH  2
#define MROWS  (BATCH * S_LEN)   // 4096

#define NEG_BIG (-1.0e30f)

__device__ inline bf16x8 cvt8_f32_bf16(const float* __restrict__ p) {
  float4 f0 = *(const float4*)(p);
  float4 f1 = *(const float4*)(p + 4);
  bf16x8 r;
  r[0] = (bf16_t)f0.x; r[1] = (bf16_t)f0.y; r[2] = (bf16_t)f0.z; r[3] = (bf16_t)f0.w;
  r[4] = (bf16_t)f1.x; r[5] = (bf16_t)f1.y; r[6] = (bf16_t)f1.z; r[7] = (bf16_t)f1.w;
  return r;
}

// ---------------- GEMM: C = A @ W^T + bias ----------------
// A [M,K] (TA = float or bf16), W [N,K] fp32, bias fp32.
// mode 0: C[row*N + col]              (plain; TC=float for final output)
// mode 1: ((b*NH+h)*S + s)*DH + d     (split heads, Q/K; TC=bf16)
// mode 2: ((b*NH+h)*DH + d)*S + s     (split heads transposed, V; TC=bf16)
template <typename TA, typename TC>
__global__ __launch_bounds__(256)
void gemm_bt(const TA* __restrict__ A, const float* __restrict__ W,
             const float* __restrict__ bias, TC* __restrict__ C, int mode)
{
  constexpr int K = DMODEL, N = DMODEL;
  __shared__ __align__(16) bf16_t As[128 * 40];  // rows padded 32->40
  __shared__ __align__(16) bf16_t Bs[128 * 40];
  const int tid  = threadIdx.x;
  const int wave = tid >> 6, lane = tid & 63;
  const int quad = lane >> 4, l16 = lane & 15;
  const int bm = blockIdx.x * 128, bn = blockIdx.y * 128;
  const int wm = (wave >> 1) * 64, wn = (wave & 1) * 64;

  f32x4 acc[4][4] = {};

  for (int k0 = 0; k0 < K; k0 += 32) {
#pragma unroll
    for (int i = 0; i < 2; ++i) {          // 512 chunks of 8 elems, 2 per thread
      int c = tid + i * 256;
      int row = c >> 2, kc = (c & 3) << 3;
      // A tile (convert fp32 -> bf16 if needed)
      if constexpr (__is_same(TA, float)) {
        *(bf16x8*)(&As[row * 40 + kc]) =
            cvt8_f32_bf16(&A[(size_t)(bm + row) * K + k0 + kc]);
      } else {
        *(float4*)(&As[row * 40 + kc]) =
            *(const float4*)(&A[(size_t)(bm + row) * K + k0 + kc]);
      }
      // W tile (always fp32 -> bf16)
      *(bf16x8*)(&Bs[row * 40 + kc]) =
          cvt8_f32_bf16(&W[(size_t)(bn + row) * K + k0 + kc]);
    }
    __syncthreads();
    bf16x8 af[4], bfr[4];
#pragma unroll
    for (int i = 0; i < 4; ++i) {
      af[i]  = *(const bf16x8*)(&As[(wm + i * 16 + l16) * 40 + quad * 8]);
      bfr[i] = *(const bf16x8*)(&Bs[(wn + i * 16 + l16) * 40 + quad * 8]);
    }
#pragma unroll
    for (int mi = 0; mi < 4; ++mi)
#pragma unroll
      for (int ni = 0; ni < 4; ++ni)
        acc[mi][ni] = __builtin_amdgcn_mfma_f32_16x16x32_bf16(
            af[mi], bfr[ni], acc[mi][ni], 0, 0, 0);
    __syncthreads();
  }

#pragma unroll
  for (int mi = 0; mi < 4; ++mi) {
#pragma unroll
    for (int ni = 0; ni < 4; ++ni) {
      int col = bn + wn + ni * 16 + l16;
      float bval = bias[col];
#pragma unroll
      for (int r = 0; r < 4; ++r) {
        int row = bm + wm + mi * 16 + quad * 4 + r;   // C row = quad*4+r (m89/m91)
        float vv = acc[mi][ni][r] + bval;
        size_t idx;
        if (mode == 0) {
          idx = (size_t)row * N + col;
        } else {
          int b = row >> 11, s = row & (S_LEN - 1);
          int h = col >> 7,  d = col & (DH - 1);
          if (mode == 1) idx = (((size_t)(b * NH + h)) * S_LEN + s) * DH + d;
          else           idx = (((size_t)(b * NH + h)) * DH + d) * S_LEN + s;
        }
        C[idx] = (TC)vv;
      }
    }
  }
}

// ---------------- Flash attention ----------------
// Q,K: [B*NH, S, DH] bf16   V: [B*NH, DH, S] bf16 (transposed)   O: [B, S, D] bf16
// Block: 64 Q-rows (4 waves x 16), iterate 64-key tiles with online softmax.
__global__ __launch_bounds__(256)
void attn_fwd(const bf16_t* __restrict__ Q, const bf16_t* __restrict__ Kh,
              const bf16_t* __restrict__ Vt, bf16_t* __restrict__ O,
              const int* __restrict__ causal_p)
{
  __shared__ __align__(16) bf16_t Ks[64 * 136];   // [key][dh], rows padded 128->136
  __shared__ __align__(16) bf16_t Vs[128 * 72];   // [dh][key], rows padded 64->72
  __shared__ __align__(16) bf16_t Ps[4][16 * 72]; // per-wave P tile [qrow][key]
  const int tid  = threadIdx.x;
  const int wave = tid >> 6, lane = tid & 63;
  const int quad = lane >> 4, l16 = lane & 15;
  const int qb = blockIdx.x, bh = blockIdx.y;
  const int causal = *causal_p;
  const float scale = 0.08838834764831845f;   // 1/sqrt(128)

  const bf16_t* Qb = Q  + ((size_t)bh * S_LEN + qb * 64) * DH;
  const bf16_t* Kb = Kh + (size_t)bh * S_LEN * DH;
  const bf16_t* Vb = Vt + (size_t)bh * DH * S_LEN;

  bf16x8 qf[4];   // A-frags of this wave's 16 Q-rows, full DH=128
#pragma unroll
  for (int kk = 0; kk < 4; ++kk)
    qf[kk] = *(const bf16x8*)(&Qb[(wave * 16 + l16) * DH + kk * 32 + quad * 8]);

  f32x4 oacc[8] = {};
  float mrow[4] = {NEG_BIG, NEG_BIG, NEG_BIG, NEG_BIG};
  float lrow[4] = {0.f, 0.f, 0.f, 0.f};

  const int nkb = causal ? (qb + 1) : (S_LEN / 64);
  for (int kb = 0; kb < nkb; ++kb) {
    // stage K tile [64][128]
#pragma unroll
    for (int i = 0; i < 4; ++i) {
      int c = tid + i * 256;
      int row = c >> 4, off = (c & 15) << 3;
      *(float4*)(&Ks[row * 136 + off]) =
          *(const float4*)(&Kb[(size_t)(kb * 64 + row) * DH + off]);
    }
    // stage V tile [128 dh][64 key] (already transposed in global)
#pragma unroll
    for (int i = 0; i < 4; ++i) {
      int c = tid + i * 256;
      int row = c >> 3, off = (c & 7) << 3;
      *(float4*)(&Vs[row * 72 + off]) =
          *(const float4*)(&Vb[(size_t)row * S_LEN + kb * 64 + off]);
    }
    __syncthreads();

    // scores S = Q Kt : 16x64 per wave
    f32x4 sc[4] = {};
#pragma unroll
    for (int kk = 0; kk < 4; ++kk) {
      bf16x8 kf[4];
#pragma unroll
      for (int nf = 0; nf < 4; ++nf)
        kf[nf] = *(const bf16x8*)(&Ks[(nf * 16 + l16) * 136 + kk * 32 + quad * 8]);
#pragma unroll
      for (int nf = 0; nf < 4; ++nf)
        sc[nf] = __builtin_amdgcn_mfma_f32_16x16x32_bf16(qf[kk], kf[nf], sc[nf], 0, 0, 0);
    }

    // mask + scale (finite sentinel: no inf anywhere -> NaN impossible)
    float p[4][4];  // [nf][r]
#pragma unroll
    for (int r = 0; r < 4; ++r) {
      int qrow = qb * 64 + wave * 16 + quad * 4 + r;
#pragma unroll
      for (int nf = 0; nf < 4; ++nf) {
        int key = kb * 64 + nf * 16 + l16;
        float s = sc[nf][r] * scale;
        if (causal && key > qrow) s = NEG_BIG;
        p[nf][r] = s;
      }
    }
    // online softmax per row (row quad*4+r lives in this quad's 16 lanes)
#pragma unroll
    for (int r = 0; r < 4; ++r) {
      float mx = fmaxf(fmaxf(p[0][r], p[1][r]), fmaxf(p[2][r], p[3][r]));
#pragma unroll
      for (int d = 8; d >= 1; d >>= 1) mx = fmaxf(mx, __shfl_xor(mx, d));
      float mnew  = fmaxf(mrow[r], mx);          // always finite
      float alpha = __expf(mrow[r] - mnew);      // finite - finite
      mrow[r] = mnew;
      float rsum = 0.f;
#pragma unroll
      for (int nf = 0; nf < 4; ++nf) {
        float e = __expf(p[nf][r] - mnew);       // <= 0, finite
        p[nf][r] = e;
        rsum += e;
      }
#pragma unroll
      for (int d = 8; d >= 1; d >>= 1) rsum += __shfl_xor(rsum, d);
      lrow[r] = lrow[r] * alpha + rsum;
#pragma unroll
      for (int nf = 0; nf < 8; ++nf) oacc[nf][r] *= alpha;
    }

    // P: C-layout -> A-layout via LDS round-trip (full barrier for safety)
    bf16_t* Pw = &Ps[wave][0];
#pragma unroll
    for (int r = 0; r < 4; ++r)
#pragma unroll
      for (int nf = 0; nf < 4; ++nf)
        Pw[(quad * 4 + r) * 72 + nf * 16 + l16] = (bf16_t)p[nf][r];
    __syncthreads();   // nkb is block-uniform -> safe inside loop

    // O += P V : A = P[16x64], B = V[64 x 128] read from Vs[dh][key]
#pragma unroll
    for (int ks = 0; ks < 2; ++ks) {
      bf16x8 pf = *(const bf16x8*)(&Pw[l16 * 72 + ks * 32 + quad * 8]);
#pragma unroll
      for (int nf = 0; nf < 8; ++nf) {
        bf16x8 vf = *(const bf16x8*)(&Vs[(nf * 16 + l16) * 72 + ks * 32 + quad * 8]);
        oacc[nf] = __builtin_amdgcn_mfma_f32_16x16x32_bf16(pf, vf, oacc[nf], 0, 0, 0);
      }
    }
    __syncthreads();   // protect Ks/Vs/Ps before next iteration
  }

  // epilogue: O[b, s, h*DH + dh] = oacc / l
  const int b = bh >> 4, h = bh & 15;
#pragma unroll
  for (int nf = 0; nf < 8; ++nf) {
    int dh = nf * 16 + l16;
#pragma unroll
    for (int r = 0; r < 4; ++r) {
      int s = qb * 64 + wave * 16 + quad * 4 + r;
      float vv = oacc[nf][r] / fmaxf(lrow[r], 1e-20f);
      O[((size_t)(b * S_LEN + s)) * DMODEL + h * DH + dh] = (bf16_t)vv;
    }
  }
}

extern "C" void kernel_launch(void* const* d_in, const int* in_sizes, int n_in,
                              void* d_out, int out_size, void* d_ws, size_t ws_size,
                              hipStream_t stream) {
  const float* q  = (const float*)d_in[0];    // fp32 per reference
  const float* k  = (const float*)d_in[1];
  const float* v  = (const float*)d_in[2];
  const float* Wq = (const float*)d_in[3];
  const float* bq = (const float*)d_in[4];
  const float* Wk = (const float*)d_in[5];
  const float* bk = (const float*)d_in[6];
  const float* Wv = (const float*)d_in[7];
  const float* bv = (const float*)d_in[8];
  const float* Wo = (const float*)d_in[9];
  const float* bo = (const float*)d_in[10];
  const int*   cm = (const int*)d_in[11];

  float* out = (float*)d_out;                 // fp32 output
  const size_t NELEM = (size_t)MROWS * DMODEL;   // 8,388,608 per tensor
  bf16_t* Qh = (bf16_t*)d_ws;        // [B,H,S,DH]  bf16 intermediates
  bf16_t* Kh = Qh + NELEM;           // [B,H,S,DH]
  bf16_t* Vh = Kh + NELEM;           // [B,H,DH,S] (transposed)
  bf16_t* Ao = Vh + NELEM;           // [B,S,D]    total ws use: 64 MiB

  dim3 gg(MROWS / 128, DMODEL / 128), bb(256);
  gemm_bt<float, bf16_t><<<gg, bb, 0, stream>>>(q, Wq, bq, Qh, 1);
  gemm_bt<float, bf16_t><<<gg, bb, 0, stream>>>(k, Wk, bk, Kh, 1);
  gemm_bt<float, bf16_t><<<gg, bb, 0, stream>>>(v, Wv, bv, Vh, 2);
  attn_fwd<<<dim3(S_LEN / 64, BATCH * NH), bb, 0, stream>>>(Qh, Kh, Vh, Ao, cm);
  gemm_bt<bf16_t, float><<<gg, bb, 0, stream>>>(Ao, Wo, bo, out, 0);
}